// Round 15
// baseline (799.606 us; speedup 1.0000x reference)
//
#include <hip/hip_runtime.h>
#include <math.h>

namespace {

typedef _Float16 f16;
typedef _Float16 f16x8 __attribute__((ext_vector_type(8)));
typedef float    f32x4 __attribute__((ext_vector_type(4)));

constexpr int kBT = 1024, kD1 = 256, kD2 = 128, kDM = 1024, kV = 32000, kK = 4;
constexpr int AR = kBT * kK;                    // 4096 rows of (bt,k)
constexpr int ROWS_H = kK * kDM;                // 4096
constexpr int ROWS_U = kK * kD2;                // 512
constexpr int ROWS_ALL = ROWS_H + ROWS_U + kK;  // 4612
constexpr int SLICES = 8;
constexpr int SLICE_ROWS = (ROWS_ALL + SLICES - 1) / SLICES;  // 577
constexpr int NBY = kV / 128;                   // 250 v-panels

// ---------------------------------------------------------------------------
// prep_gemm: hc/tU/ug from gc (fp32 accumulate, fp16 store). Grid (128,8).
// ---------------------------------------------------------------------------
__global__ __launch_bounds__(256) void prep_gemm(
    const float* __restrict__ gc, const float* __restrict__ Hm,
    const float* __restrict__ Um, const float* __restrict__ um,
    f16* __restrict__ hc, f16* __restrict__ tu, float* __restrict__ ug)
{
    __shared__ float sgc[8][kD1];
    const int btBase = blockIdx.x * 8;
    for (int idx = threadIdx.x; idx < 8 * kD1; idx += 256)
        sgc[idx / kD1][idx % kD1] = gc[(size_t)btBase * kD1 + idx];
    __syncthreads();

    const int rStart = blockIdx.y * SLICE_ROWS;
    int rEnd = rStart + SLICE_ROWS;
    if (rEnd > ROWS_ALL) rEnd = ROWS_ALL;
    for (int r = rStart + (int)threadIdx.x; r < rEnd; r += 256) {
        const float* wrow;
        if (r < ROWS_H)               wrow = Hm + (size_t)r * kD1;
        else if (r < ROWS_H + ROWS_U) wrow = Um + (size_t)(r - ROWS_H) * kD1;
        else                          wrow = um + (size_t)(r - ROWS_H - ROWS_U) * kD1;

        float acc[8] = {0.f,0.f,0.f,0.f,0.f,0.f,0.f,0.f};
        for (int i = 0; i < kD1; i += 4) {
            const float4 w = *reinterpret_cast<const float4*>(wrow + i);
            #pragma unroll
            for (int b = 0; b < 8; ++b) {
                const float4 g = *reinterpret_cast<const float4*>(&sgc[b][i]);
                acc[b] = fmaf(w.x, g.x, acc[b]);
                acc[b] = fmaf(w.y, g.y, acc[b]);
                acc[b] = fmaf(w.z, g.z, acc[b]);
                acc[b] = fmaf(w.w, g.w, acc[b]);
            }
        }
        #pragma unroll
        for (int b = 0; b < 8; ++b) {
            const int bt = btBase + b;
            if (r < ROWS_H) {
                const int k = r >> 10, d = r & 1023;
                hc[((size_t)(bt * kK + k) << 10) + d] = (f16)tanhf(acc[b]);
            } else if (r < ROWS_H + ROWS_U) {
                const int r2 = r - ROWS_H;
                const int k = r2 >> 7, j = r2 & 127;
                tu[(size_t)(bt * kK + k) * kD2 + j] = (f16)tanhf(acc[b]);
            } else {
                ug[bt * kK + (r - ROWS_H - ROWS_U)] = acc[b];
            }
        }
    }
}

// ---------------------------------------------------------------------------
// cvt_kernel: fp32 -> fp16, 8 elems/thread.
// ---------------------------------------------------------------------------
__global__ __launch_bounds__(256) void cvt_kernel(
    const float* __restrict__ src, f16* __restrict__ dst, int n8)
{
    const int i = blockIdx.x * 256 + threadIdx.x;
    if (i >= n8) return;
    const float4 x0 = *reinterpret_cast<const float4*>(src + (size_t)i * 8);
    const float4 x1 = *reinterpret_cast<const float4*>(src + (size_t)i * 8 + 4);
    union { f16 h[8]; uint4 v; } u;
    u.h[0] = (f16)x0.x; u.h[1] = (f16)x0.y; u.h[2] = (f16)x0.z; u.h[3] = (f16)x0.w;
    u.h[4] = (f16)x1.x; u.h[5] = (f16)x1.y; u.h[6] = (f16)x1.z; u.h[7] = (f16)x1.w;
    *reinterpret_cast<uint4*>(dst + (size_t)i * 8) = u.v;
}

__device__ __forceinline__ uint packf16x2(float a, float b) {
    union { f16 h[2]; uint u; } z;
    z.h[0] = (f16)a; z.h[1] = (f16)b;
    return z.u;
}

// ---------------------------------------------------------------------------
// fused_mfma: gate GEMM (K=128, 2 tiles) + dots GEMM (K=1024, 16 tiles).
// Round-14 structure EXCEPT: B operand now loaded L2->REGISTERS (B0/B1
// double buffer, statically indexed), LDS holds A only (32 KiB).
// Rationale: round-14 was LDS-BW-bound (64KB read + 16KB write per
// block-tile ~= 1880cyc/pair at 85 B/cyc = measured period). A-only LDS
// = 48 KB/block-tile. B panel (256KB/by) is L2-resident (32 bx share it).
// Ledger: stage(t+1) = 4 A-gload_lds + 8 B-reg-loads = 12 VMEM ops;
// vmcnt(12) before bar retires ALL of tile t's ops (A in LDS + B regs).
// B-reg RAW additionally compiler-guarded (register dest); B-reg WAR is
// program-order (regs private); A-LDS WAR same barrier proof as r13/14.
// pi block's scalar loads force one compiler vmcnt(0) drain (once, OK).
// Register budget: acc 64 + pi 32 + B0/B1 64 + bases ~30 => ~190 < 256.
// ---------------------------------------------------------------------------
__global__ __launch_bounds__(256, 2) void fused_mfma(
    const f16* __restrict__ hc,  const f16* __restrict__ tu,
    const f16* __restrict__ v16, const f16* __restrict__ e16,
    const float* __restrict__ ug, const float* __restrict__ bmat,
    float* __restrict__ out, float* __restrict__ psum)
{
    __shared__ __align__(16) f16 sA[2][128 * 64];   // 32 KiB (A only)

    const int tid  = threadIdx.x;
    const int lane = tid & 63;
    const int wave = tid >> 6;
    const int fr = lane & 15, fq = lane >> 4;
    const int wrow = wave >> 1, wcol = wave & 1;
    const int aRowBase = blockIdx.x * 128;
    const int vBase    = blockIdx.y * 128;
    const int btB      = blockIdx.x * 32 + wrow * 16;

    // A staging: chunk c = wave*4+i covers 8 rows; lane l -> row l>>3,
    // phys slot l&7 holds logical (l&7)^(srow&7) (inverse swizzle).
    const int srow = lane >> 3;
    const int scol = ((lane & 7) ^ srow) * 8;

    const f16* gApt = tu + (size_t)(aRowBase + wave * 32 + srow) * kD2 + scol;
    const f16* sApt = hc + (size_t)(aRowBase + wave * 32 + srow) * kDM + scol;

    // B register-load bases (per-lane fragment address; fragment layout
    // matches MFMA B operand: row = wcol*64 + n*16 + fr, col = kk*32+fq*8).
    const f16* gBpt = v16 + (size_t)(vBase + wcol * 64 + fr) * kD2 + fq * 8;
    const f16* sBpt = e16 + (size_t)(vBase + wcol * 64 + fr) * kDM + fq * 8;

    f16* dA = &sA[0][0] + wave * 4 * 512;   // + buf*8192 + i*512

#define GLD(SRC, DST)                                                         \
    __builtin_amdgcn_global_load_lds(                                         \
        (const __attribute__((address_space(1))) void*)(SRC),                 \
        (__attribute__((address_space(3))) void*)(DST), 16, 0, 0)

    f16x8 B0[8], B1[8];   // [kk*4+n], double-buffered across tiles

    auto stage_gate = [&](int t, f16x8 (&Bq)[8]) {   // t = 0,1 -> buf t
        #pragma unroll
        for (int i = 0; i < 4; ++i)
            GLD(gApt + t * 64 + i * 8 * kD2, dA + t * 8192 + i * 512);
        #pragma unroll
        for (int kk = 0; kk < 2; ++kk)
            #pragma unroll
            for (int n = 0; n < 4; ++n)
                Bq[kk * 4 + n] = *reinterpret_cast<const f16x8*>(
                    gBpt + t * 64 + (size_t)n * 16 * kD2 + kk * 32);
    };
    auto stage_dots = [&](int buf, f16x8 (&Bq)[8]) {  // running pointers
        #pragma unroll
        for (int i = 0; i < 4; ++i)
            GLD(sApt + i * 8 * kDM, dA + buf * 8192 + i * 512);
        #pragma unroll
        for (int kk = 0; kk < 2; ++kk)
            #pragma unroll
            for (int n = 0; n < 4; ++n)
                Bq[kk * 4 + n] = *reinterpret_cast<const f16x8*>(
                    sBpt + (size_t)n * 16 * kDM + kk * 32);
        sApt += 64; sBpt += 64;
    };

    // lane-constant A read bases: ps(kk) = (kk*4+fq)^(fr&7).
    const int ps0 = (fq ^ (fr & 7)) * 8;
    const int ps1 = ((4 + fq) ^ (fr & 7)) * 8;
    const f16* rA0 = &sA[0][0] + (wrow * 64 + fr) * 64 + ps0;
    const f16* rA1 = &sA[0][0] + (wrow * 64 + fr) * 64 + ps1;

    auto mmStep = [&](f32x4 (&acc)[4][4], int q, const f16x8 (&Bq)[8]) {
        const int qo = q * 8192;
        {
            f16x8 a[4];
            #pragma unroll
            for (int m = 0; m < 4; ++m)
                a[m] = *reinterpret_cast<const f16x8*>(rA0 + qo + m * 1024);
            __builtin_amdgcn_s_setprio(1);
            #pragma unroll
            for (int m = 0; m < 4; ++m)
                #pragma unroll
                for (int n = 0; n < 4; ++n)
                    acc[m][n] = __builtin_amdgcn_mfma_f32_16x16x32_f16(
                        a[m], Bq[n], acc[m][n], 0, 0, 0);
            __builtin_amdgcn_s_setprio(0);
        }
        {
            f16x8 a[4];
            #pragma unroll
            for (int m = 0; m < 4; ++m)
                a[m] = *reinterpret_cast<const f16x8*>(rA1 + qo + m * 1024);
            __builtin_amdgcn_s_setprio(1);
            #pragma unroll
            for (int m = 0; m < 4; ++m)
                #pragma unroll
                for (int n = 0; n < 4; ++n)
                    acc[m][n] = __builtin_amdgcn_mfma_f32_16x16x32_f16(
                        a[m], Bq[4 + n], acc[m][n], 0, 0, 0);
            __builtin_amdgcn_s_setprio(0);
        }
    };

#define WAITBAR(VM)                                                           \
    asm volatile("s_waitcnt vmcnt(" VM ")" ::: "memory");                     \
    __builtin_amdgcn_s_barrier();                                             \
    asm volatile("" ::: "memory");
#define ENDBAR                                                                \
    asm volatile("" ::: "memory");                                            \
    __builtin_amdgcn_s_barrier();                                             \
    asm volatile("" ::: "memory");

    const f32x4 zz = {0.f, 0.f, 0.f, 0.f};

    // ---------------- gate phase: tiles 0,1 over D2 ----------------
    f32x4 gacc[4][4];
    #pragma unroll
    for (int m = 0; m < 4; ++m)
        #pragma unroll
        for (int n = 0; n < 4; ++n) gacc[m][n] = zz;

    stage_gate(0, B0);
    stage_gate(1, B1);      WAITBAR("12")  mmStep(gacc, 0, B0);  ENDBAR
    stage_dots(0, B0);      WAITBAR("12")  mmStep(gacc, 1, B1);  ENDBAR

    // ---------------- pi conversion (registers only) ----------------
    uint pi01[4][4], pi23[4][4];
    {
        float4 bb[4];
        #pragma unroll
        for (int n = 0; n < 4; ++n)
            bb[n] = *reinterpret_cast<const float4*>(
                bmat + (size_t)(vBase + wcol * 64 + n * 16 + fr) * 4);
        #pragma unroll
        for (int m = 0; m < 4; ++m) {
            const float4 ugv = *reinterpret_cast<const float4*>(
                ug + (btB + m * 4 + fq) * 4);
            #pragma unroll
            for (int n = 0; n < 4; ++n) {
                const float l0 = gacc[m][n][0] + ugv.x + bb[n].x;
                const float l1 = gacc[m][n][1] + ugv.y + bb[n].y;
                const float l2 = gacc[m][n][2] + ugv.z + bb[n].z;
                const float g0 = 1.f / (1.f + __expf(-l0));
                const float g1 = 1.f / (1.f + __expf(-l1));
                const float g2 = 1.f / (1.f + __expf(-l2));
                pi01[m][n] = packf16x2(g0 * g1, g0 * (1.f - g1));
                pi23[m][n] = packf16x2((1.f - g0) * g2, (1.f - g0) * (1.f - g2));
            }
        }
    }

    // ---------------- dots phase: 16 tiles over DM ----------------
    f32x4 dacc[4][4];
    #pragma unroll
    for (int m = 0; m < 4; ++m)
        #pragma unroll
        for (int n = 0; n < 4; ++n) dacc[m][n] = zz;

    for (int it = 0; it < 7; ++it) {
        stage_dots(1, B1);  WAITBAR("12")  mmStep(dacc, 0, B0);  ENDBAR
        stage_dots(0, B0);  WAITBAR("12")  mmStep(dacc, 1, B1);  ENDBAR
    }
    stage_dots(1, B1);      WAITBAR("12")  mmStep(dacc, 0, B0);  ENDBAR
                            WAITBAR("0")   mmStep(dacc, 1, B1);
#undef WAITBAR
#undef ENDBAR
#undef GLD

    // ---------------- epilogue: logits + exp partial sums ----------------
    #pragma unroll
    for (int m = 0; m < 4; ++m) {
        const int bt = btB + m * 4 + fq;
        float es = 0.f;
        #pragma unroll
        for (int n = 0; n < 4; ++n) {
            const int v = vBase + wcol * 64 + n * 16 + fr;
            union { uint u; f16 h[2]; } p01, p23;
            p01.u = pi01[m][n]; p23.u = pi23[m][n];
            const float lg = (float)p01.h[0] * dacc[m][n][0]
                           + (float)p01.h[1] * dacc[m][n][1]
                           + (float)p23.h[0] * dacc[m][n][2]
                           + (float)p23.h[1] * dacc[m][n][3];
            out[(size_t)bt * kV + v] = lg;
            es += __expf(lg);
        }
        es += __shfl_xor(es, 1);
        es += __shfl_xor(es, 2);
        es += __shfl_xor(es, 4);
        es += __shfl_xor(es, 8);
        if (fr == 0)
            psum[(size_t)bt * 512 + blockIdx.y * 2 + wcol] = es;
    }
}

// ---------------------------------------------------------------------------
// softmax scale pass: denominator from psum partials.
// ---------------------------------------------------------------------------
__global__ __launch_bounds__(256) void softmax_kernel(
    float* __restrict__ out, const float* __restrict__ psum)
{
    __shared__ float red[4];
    const int bt = blockIdx.x;
    float* row = out + (size_t)bt * kV;
    const int tid = threadIdx.x;

    float s = 0.f;
    for (int i = tid; i < 2 * NBY; i += 256) s += psum[(size_t)bt * 512 + i];
    #pragma unroll
    for (int o = 1; o < 64; o <<= 1) s += __shfl_xor(s, o);
    if ((tid & 63) == 0) red[tid >> 6] = s;
    __syncthreads();
    s = red[0] + red[1] + red[2] + red[3];
    const float inv = 1.f / s;

    for (int i = tid * 4; i < kV; i += 1024) {
        const float4 x = *reinterpret_cast<const float4*>(row + i);
        float4 y;
        y.x = __expf(x.x) * inv;
        y.y = __expf(x.y) * inv;
        y.z = __expf(x.z) * inv;
        y.w = __expf(x.w) * inv;
        *reinterpret_cast<float4*>(row + i) = y;
    }
}

} // namespace

extern "C" void kernel_launch(void* const* d_in, const int* in_sizes, int n_in,
                              void* d_out, int out_size, void* d_ws, size_t ws_size,
                              hipStream_t stream)
{
    (void)in_sizes; (void)n_in; (void)out_size; (void)ws_size;
    const float* gc   = (const float*)d_in[0];
    const float* Hm   = (const float*)d_in[1];
    const float* Um   = (const float*)d_in[2];
    const float* vmat = (const float*)d_in[3];
    const float* um   = (const float*)d_in[4];
    const float* bmat = (const float*)d_in[5];
    const float* emb  = (const float*)d_in[6];
    float* out = (float*)d_out;

    size_t off = 0;
    auto take = [&](size_t bytes) -> char* {
        char* p = (char*)d_ws + off;
        off += (bytes + 255) & ~(size_t)255;
        return p;
    };
    f16*   hc   = (f16*)  take((size_t)AR * kDM * 2);   // 8 MB
    f16*   tu   = (f16*)  take((size_t)AR * kD2 * 2);   // 1 MB
    f16*   v16  = (f16*)  take((size_t)kV * kD2 * 2);   // 8 MB
    f16*   e16  = (f16*)  take((size_t)kV * kDM * 2);   // 64 MB
    float* ug   = (float*)take((size_t)AR * 4);
    float* psum = (float*)take((size_t)kBT * 512 * 4);  // 2 MB

    prep_gemm<<<dim3(kBT / 8, SLICES), 256, 0, stream>>>(gc, Hm, Um, um, hc, tu, ug);
    cvt_kernel<<<(kV * kD2 / 8 + 255) / 256, 256, 0, stream>>>(vmat, v16, kV * kD2 / 8);
    cvt_kernel<<<(kV * kDM / 8 + 255) / 256, 256, 0, stream>>>(emb, e16, kV * kDM / 8);
    fused_mfma<<<dim3(AR / 128, NBY), 256, 0, stream>>>(
        hc, tu, v16, e16, ug, bmat, out, psum);
    softmax_kernel<<<dim3(kBT), 256, 0, stream>>>(out, psum);
}

// Round 16
// 533.711 us; speedup vs baseline: 1.4982x; 1.4982x over previous
//
#include <hip/hip_runtime.h>
#include <math.h>

namespace {

typedef _Float16 f16;
typedef _Float16 f16x8 __attribute__((ext_vector_type(8)));
typedef float    f32x4 __attribute__((ext_vector_type(4)));

constexpr int kBT = 1024, kD1 = 256, kD2 = 128, kDM = 1024, kV = 32000, kK = 4;
constexpr int AR = kBT * kK;                    // 4096 rows of (bt,k)
constexpr int ROWS_H = kK * kDM;                // 4096
constexpr int ROWS_U = kK * kD2;                // 512
constexpr int ROWS_ALL = ROWS_H + ROWS_U + kK;  // 4612
constexpr int SLICES = 8;
constexpr int SLICE_ROWS = (ROWS_ALL + SLICES - 1) / SLICES;  // 577
constexpr int NBY = kV / 128;                   // 250 v-panels

// ---------------------------------------------------------------------------
// prep_gemm: hc/tU/ug from gc (fp32 accumulate, fp16 store). Grid (128,8).
// ---------------------------------------------------------------------------
__global__ __launch_bounds__(256) void prep_gemm(
    const float* __restrict__ gc, const float* __restrict__ Hm,
    const float* __restrict__ Um, const float* __restrict__ um,
    f16* __restrict__ hc, f16* __restrict__ tu, float* __restrict__ ug)
{
    __shared__ float sgc[8][kD1];
    const int btBase = blockIdx.x * 8;
    for (int idx = threadIdx.x; idx < 8 * kD1; idx += 256)
        sgc[idx / kD1][idx % kD1] = gc[(size_t)btBase * kD1 + idx];
    __syncthreads();

    const int rStart = blockIdx.y * SLICE_ROWS;
    int rEnd = rStart + SLICE_ROWS;
    if (rEnd > ROWS_ALL) rEnd = ROWS_ALL;
    for (int r = rStart + (int)threadIdx.x; r < rEnd; r += 256) {
        const float* wrow;
        if (r < ROWS_H)               wrow = Hm + (size_t)r * kD1;
        else if (r < ROWS_H + ROWS_U) wrow = Um + (size_t)(r - ROWS_H) * kD1;
        else                          wrow = um + (size_t)(r - ROWS_H - ROWS_U) * kD1;

        float acc[8] = {0.f,0.f,0.f,0.f,0.f,0.f,0.f,0.f};
        for (int i = 0; i < kD1; i += 4) {
            const float4 w = *reinterpret_cast<const float4*>(wrow + i);
            #pragma unroll
            for (int b = 0; b < 8; ++b) {
                const float4 g = *reinterpret_cast<const float4*>(&sgc[b][i]);
                acc[b] = fmaf(w.x, g.x, acc[b]);
                acc[b] = fmaf(w.y, g.y, acc[b]);
                acc[b] = fmaf(w.z, g.z, acc[b]);
                acc[b] = fmaf(w.w, g.w, acc[b]);
            }
        }
        #pragma unroll
        for (int b = 0; b < 8; ++b) {
            const int bt = btBase + b;
            if (r < ROWS_H) {
                const int k = r >> 10, d = r & 1023;
                hc[((size_t)(bt * kK + k) << 10) + d] = (f16)tanhf(acc[b]);
            } else if (r < ROWS_H + ROWS_U) {
                const int r2 = r - ROWS_H;
                const int k = r2 >> 7, j = r2 & 127;
                tu[(size_t)(bt * kK + k) * kD2 + j] = (f16)tanhf(acc[b]);
            } else {
                ug[bt * kK + (r - ROWS_H - ROWS_U)] = acc[b];
            }
        }
    }
}

// ---------------------------------------------------------------------------
// cvt_kernel: fp32 -> fp16, 8 elems/thread.
// ---------------------------------------------------------------------------
__global__ __launch_bounds__(256) void cvt_kernel(
    const float* __restrict__ src, f16* __restrict__ dst, int n8)
{
    const int i = blockIdx.x * 256 + threadIdx.x;
    if (i >= n8) return;
    const float4 x0 = *reinterpret_cast<const float4*>(src + (size_t)i * 8);
    const float4 x1 = *reinterpret_cast<const float4*>(src + (size_t)i * 8 + 4);
    union { f16 h[8]; uint4 v; } u;
    u.h[0] = (f16)x0.x; u.h[1] = (f16)x0.y; u.h[2] = (f16)x0.z; u.h[3] = (f16)x0.w;
    u.h[4] = (f16)x1.x; u.h[5] = (f16)x1.y; u.h[6] = (f16)x1.z; u.h[7] = (f16)x1.w;
    *reinterpret_cast<uint4*>(dst + (size_t)i * 8) = u.v;
}

__device__ __forceinline__ uint packf16x2(float a, float b) {
    union { f16 h[2]; uint u; } z;
    z.h[0] = (f16)a; z.h[1] = (f16)b;
    return z.u;
}

// ---------------------------------------------------------------------------
// fused_mfma: gate GEMM (K=128, 2 tiles) + dots GEMM (K=1024, 16 tiles).
// ROUND-14 PROVEN STRUCTURE (398us fused, 108 VGPR, 0 conflicts, 2 blk/CU):
// 128x128 tile, BK=64, 4 waves (2x2), dbuf LDS 64 KiB (A and B), XOR-swizzled
// global_load_lds staging (offset imm 0, col in pointer), vmcnt(8) + raw
// s_barrier, lane-constant read bases, setprio around MFMA clusters,
// running dots pointers, psum epilogue.
// CHANGED vs round 14 (traffic only): epilogue stores logits as FP16 to a
// ws buffer (65MB not 131MB); psum accumulates exp of the SAME fp16-rounded
// values (numerator/denominator consistent). |logit|<~5 -> fp16 rounding
// delta<=4e-3 worst -> absmax delta <= p_max*4e-3 ~= 1.3e-6 (threshold
// 1.04e-5). Round-15's B-to-registers REVERTED (scattered loads, -73%).
// ---------------------------------------------------------------------------
__global__ __launch_bounds__(256, 2) void fused_mfma(
    const f16* __restrict__ hc,  const f16* __restrict__ tu,
    const f16* __restrict__ v16, const f16* __restrict__ e16,
    const float* __restrict__ ug, const float* __restrict__ bmat,
    f16* __restrict__ lg16, float* __restrict__ psum)
{
    __shared__ __align__(16) f16 sA[2][128 * 64];   // 32 KiB
    __shared__ __align__(16) f16 sB[2][128 * 64];   // 32 KiB

    const int tid  = threadIdx.x;
    const int lane = tid & 63;
    const int wave = tid >> 6;
    const int fr = lane & 15, fq = lane >> 4;
    const int wrow = wave >> 1, wcol = wave & 1;
    const int aRowBase = blockIdx.x * 128;
    const int vBase    = blockIdx.y * 128;
    const int btB      = blockIdx.x * 32 + wrow * 16;

    // staging geometry: chunk c = wave*4+i covers rows wave*32+i*8 .. +8;
    // lane l -> row srow = l>>3, phys slot l&7 holds logical (l&7)^srow.
    const int srow = lane >> 3;
    const int scol = ((lane & 7) ^ srow) * 8;   // inverse-swizzled global col

    // per-thread staging bases; dots pointers advance +64 per staged tile.
    const f16* gApt = tu  + (size_t)(aRowBase + wave * 32 + srow) * kD2 + scol;
    const f16* gBpt = v16 + (size_t)(vBase    + wave * 32 + srow) * kD2 + scol;
    const f16* sApt = hc  + (size_t)(aRowBase + wave * 32 + srow) * kDM + scol;
    const f16* sBpt = e16 + (size_t)(vBase    + wave * 32 + srow) * kDM + scol;

    f16* dA = &sA[0][0] + wave * 4 * 512;   // + buf*8192 + i*512
    f16* dB = &sB[0][0] + wave * 4 * 512;

#define GLD(SRC, DST)                                                         \
    __builtin_amdgcn_global_load_lds(                                         \
        (const __attribute__((address_space(1))) void*)(SRC),                 \
        (__attribute__((address_space(3))) void*)(DST), 16, 0, 0)

    // gate tile t (t = 0,1 literal) -> buf t.
    auto stage_gate = [&](int t) {
        #pragma unroll
        for (int i = 0; i < 4; ++i) {
            GLD(gApt + t * 64 + i * 8 * kD2, dA + t * 8192 + i * 512);
            GLD(gBpt + t * 64 + i * 8 * kD2, dB + t * 8192 + i * 512);
        }
    };
    // dots tile (running pointers) -> buf.
    auto stage_dots = [&](int buf) {
        #pragma unroll
        for (int i = 0; i < 4; ++i) {
            GLD(sApt + i * 8 * kDM, dA + buf * 8192 + i * 512);
            GLD(sBpt + i * 8 * kDM, dB + buf * 8192 + i * 512);
        }
        sApt += 64; sBpt += 64;
    };

    // lane-constant read bases: ps(kk) = (kk*4+fq)^(fr&7).
    const int ps0 = (fq ^ (fr & 7)) * 8;
    const int ps1 = ((4 + fq) ^ (fr & 7)) * 8;
    const f16* rA0 = &sA[0][0] + (wrow * 64 + fr) * 64 + ps0;
    const f16* rA1 = &sA[0][0] + (wrow * 64 + fr) * 64 + ps1;
    const f16* rB0 = &sB[0][0] + (wcol * 64 + fr) * 64 + ps0;
    const f16* rB1 = &sB[0][0] + (wcol * 64 + fr) * 64 + ps1;

    auto mmStep = [&](f32x4 (&acc)[4][4], int q) {
        const int qo = q * 8192;
        {
            f16x8 a[4], b[4];
            #pragma unroll
            for (int m = 0; m < 4; ++m)
                a[m] = *reinterpret_cast<const f16x8*>(rA0 + qo + m * 1024);
            #pragma unroll
            for (int n = 0; n < 4; ++n)
                b[n] = *reinterpret_cast<const f16x8*>(rB0 + qo + n * 1024);
            __builtin_amdgcn_s_setprio(1);
            #pragma unroll
            for (int m = 0; m < 4; ++m)
                #pragma unroll
                for (int n = 0; n < 4; ++n)
                    acc[m][n] = __builtin_amdgcn_mfma_f32_16x16x32_f16(
                        a[m], b[n], acc[m][n], 0, 0, 0);
            __builtin_amdgcn_s_setprio(0);
        }
        {
            f16x8 a[4], b[4];
            #pragma unroll
            for (int m = 0; m < 4; ++m)
                a[m] = *reinterpret_cast<const f16x8*>(rA1 + qo + m * 1024);
            #pragma unroll
            for (int n = 0; n < 4; ++n)
                b[n] = *reinterpret_cast<const f16x8*>(rB1 + qo + n * 1024);
            __builtin_amdgcn_s_setprio(1);
            #pragma unroll
            for (int m = 0; m < 4; ++m)
                #pragma unroll
                for (int n = 0; n < 4; ++n)
                    acc[m][n] = __builtin_amdgcn_mfma_f32_16x16x32_f16(
                        a[m], b[n], acc[m][n], 0, 0, 0);
            __builtin_amdgcn_s_setprio(0);
        }
    };

#define WAITBAR(VM)                                                           \
    asm volatile("s_waitcnt vmcnt(" VM ")" ::: "memory");                     \
    __builtin_amdgcn_s_barrier();                                             \
    asm volatile("" ::: "memory");
#define ENDBAR                                                                \
    asm volatile("" ::: "memory");                                            \
    __builtin_amdgcn_s_barrier();                                             \
    asm volatile("" ::: "memory");

    const f32x4 zz = {0.f, 0.f, 0.f, 0.f};

    // ---------------- gate phase: tiles 0,1 over D2 ----------------
    f32x4 gacc[4][4];
    #pragma unroll
    for (int m = 0; m < 4; ++m)
        #pragma unroll
        for (int n = 0; n < 4; ++n) gacc[m][n] = zz;

    stage_gate(0);
    stage_gate(1);          WAITBAR("8")  mmStep(gacc, 0);  ENDBAR
    stage_dots(0);          WAITBAR("8")  mmStep(gacc, 1);  ENDBAR

    // ---------------- pi conversion (registers only) ----------------
    uint pi01[4][4], pi23[4][4];
    {
        float4 bb[4];
        #pragma unroll
        for (int n = 0; n < 4; ++n)
            bb[n] = *reinterpret_cast<const float4*>(
                bmat + (size_t)(vBase + wcol * 64 + n * 16 + fr) * 4);
        #pragma unroll
        for (int m = 0; m < 4; ++m) {
            const float4 ugv = *reinterpret_cast<const float4*>(
                ug + (btB + m * 4 + fq) * 4);
            #pragma unroll
            for (int n = 0; n < 4; ++n) {
                const float l0 = gacc[m][n][0] + ugv.x + bb[n].x;
                const float l1 = gacc[m][n][1] + ugv.y + bb[n].y;
                const float l2 = gacc[m][n][2] + ugv.z + bb[n].z;
                const float g0 = 1.f / (1.f + __expf(-l0));
                const float g1 = 1.f / (1.f + __expf(-l1));
                const float g2 = 1.f / (1.f + __expf(-l2));
                pi01[m][n] = packf16x2(g0 * g1, g0 * (1.f - g1));
                pi23[m][n] = packf16x2((1.f - g0) * g2, (1.f - g0) * (1.f - g2));
            }
        }
    }

    // ---------------- dots phase: 16 tiles over DM ----------------
    f32x4 dacc[4][4];
    #pragma unroll
    for (int m = 0; m < 4; ++m)
        #pragma unroll
        for (int n = 0; n < 4; ++n) dacc[m][n] = zz;

    for (int it = 0; it < 7; ++it) {
        stage_dots(1);      WAITBAR("8")  mmStep(dacc, 0);  ENDBAR
        stage_dots(0);      WAITBAR("8")  mmStep(dacc, 1);  ENDBAR
    }
    stage_dots(1);          WAITBAR("8")  mmStep(dacc, 0);  ENDBAR
                            WAITBAR("0")  mmStep(dacc, 1);
#undef WAITBAR
#undef ENDBAR
#undef GLD

    // -------- epilogue: fp16 logits + exp partial sums (consistent) --------
    #pragma unroll
    for (int m = 0; m < 4; ++m) {
        const int bt = btB + m * 4 + fq;
        float es = 0.f;
        #pragma unroll
        for (int n = 0; n < 4; ++n) {
            const int v = vBase + wcol * 64 + n * 16 + fr;
            union { uint u; f16 h[2]; } p01, p23;
            p01.u = pi01[m][n]; p23.u = pi23[m][n];
            const float lg = (float)p01.h[0] * dacc[m][n][0]
                           + (float)p01.h[1] * dacc[m][n][1]
                           + (float)p23.h[0] * dacc[m][n][2]
                           + (float)p23.h[1] * dacc[m][n][3];
            const f16 lh = (f16)lg;                 // round once...
            lg16[(size_t)bt * kV + v] = lh;
            es += __expf((float)lh);                // ...sum the rounded value
        }
        es += __shfl_xor(es, 1);
        es += __shfl_xor(es, 2);
        es += __shfl_xor(es, 4);
        es += __shfl_xor(es, 8);
        if (fr == 0)
            psum[(size_t)bt * 512 + blockIdx.y * 2 + wcol] = es;
    }
}

// ---------------------------------------------------------------------------
// softmax scale pass: denom from psum partials; reads fp16 logits (65MB),
// writes fp32 probs (131MB).
// ---------------------------------------------------------------------------
__global__ __launch_bounds__(256) void softmax_kernel(
    float* __restrict__ out, const f16* __restrict__ lg16,
    const float* __restrict__ psum)
{
    __shared__ float red[4];
    const int bt = blockIdx.x;
    const f16* row16 = lg16 + (size_t)bt * kV;
    float* row = out + (size_t)bt * kV;
    const int tid = threadIdx.x;

    float s = 0.f;
    for (int i = tid; i < 2 * NBY; i += 256) s += psum[(size_t)bt * 512 + i];
    #pragma unroll
    for (int o = 1; o < 64; o <<= 1) s += __shfl_xor(s, o);
    if ((tid & 63) == 0) red[tid >> 6] = s;
    __syncthreads();
    s = red[0] + red[1] + red[2] + red[3];
    const float inv = 1.f / s;

    for (int i = tid * 8; i < kV; i += 2048) {
        union { uint4 v; f16 h[8]; } u;
        u.v = *reinterpret_cast<const uint4*>(row16 + i);
        float4 y0, y1;
        y0.x = __expf((float)u.h[0]) * inv;
        y0.y = __expf((float)u.h[1]) * inv;
        y0.z = __expf((float)u.h[2]) * inv;
        y0.w = __expf((float)u.h[3]) * inv;
        y1.x = __expf((float)u.h[4]) * inv;
        y1.y = __expf((float)u.h[5]) * inv;
        y1.z = __expf((float)u.h[6]) * inv;
        y1.w = __expf((float)u.h[7]) * inv;
        *reinterpret_cast<float4*>(row + i)     = y0;
        *reinterpret_cast<float4*>(row + i + 4) = y1;
    }
}

} // namespace

extern "C" void kernel_launch(void* const* d_in, const int* in_sizes, int n_in,
                              void* d_out, int out_size, void* d_ws, size_t ws_size,
                              hipStream_t stream)
{
    (void)in_sizes; (void)n_in; (void)out_size; (void)ws_size;
    const float* gc   = (const float*)d_in[0];
    const float* Hm   = (const float*)d_in[1];
    const float* Um   = (const float*)d_in[2];
    const float* vmat = (const float*)d_in[3];
    const float* um   = (const float*)d_in[4];
    const float* bmat = (const float*)d_in[5];
    const float* emb  = (const float*)d_in[6];
    float* out = (float*)d_out;

    size_t off = 0;
    auto take = [&](size_t bytes) -> char* {
        char* p = (char*)d_ws + off;
        off += (bytes + 255) & ~(size_t)255;
        return p;
    };
    f16*   hc   = (f16*)  take((size_t)AR * kDM * 2);   //  8 MB
    f16*   tu   = (f16*)  take((size_t)AR * kD2 * 2);   //  1 MB
    f16*   v16  = (f16*)  take((size_t)kV * kD2 * 2);   //  8 MB
    f16*   e16  = (f16*)  take((size_t)kV * kDM * 2);   // 64 MB
    float* ug   = (float*)take((size_t)AR * 4);
    float* psum = (float*)take((size_t)kBT * 512 * 4);  //  2 MB
    f16*   lg16 = (f16*)  take((size_t)kBT * kV * 2);   // 64 MB

    prep_gemm<<<dim3(kBT / 8, SLICES), 256, 0, stream>>>(gc, Hm, Um, um, hc, tu, ug);
    cvt_kernel<<<(kV * kD2 / 8 + 255) / 256, 256, 0, stream>>>(vmat, v16, kV * kD2 / 8);
    cvt_kernel<<<(kV * kDM / 8 + 255) / 256, 256, 0, stream>>>(emb, e16, kV * kDM / 8);
    fused_mfma<<<dim3(AR / 128, NBY), 256, 0, stream>>>(
        hc, tu, v16, e16, ug, bmat, lg16, psum);
    softmax_kernel<<<dim3(kBT), 256, 0, stream>>>(out, lg16, psum);
}